// Round 9
// baseline (1129.407 us; speedup 1.0000x reference)
//
#include <hip/hip_runtime.h>
#include <hip/hip_bf16.h>

// MoE top-2 of 8 experts. N=8192 tokens, D=1024, F=2048.
// R9: SAME 256x256/BK64/8-wave 2-phase structure as R8, two fixes:
//  (a) STATIC double-buffer: As0/As1/Bs0/Bs1 as separately-named __shared__
//      arrays, K-loop unrolled by 2 -> compiler can prove global_load_lds
//      (next tile) doesn't alias ds_read (current tile) and stops inserting
//      a hidden vmcnt(0) before compute (the serializer in R4-R8).
//  (b) no XCD swizzle (R8's mapped GEMM2's live blocks to even XCDs only).

#define N_TOK 8192
#define DIM   1024
#define FF    2048
#define NE    8

typedef unsigned short ushort_t;
typedef __bf16 bf16x8 __attribute__((ext_vector_type(8)));
typedef float  f32x4  __attribute__((ext_vector_type(4)));
typedef unsigned short u16x8 __attribute__((ext_vector_type(8)));

__device__ __forceinline__ ushort_t f2bf(float f) {
    union { float f; unsigned int u; } v; v.f = f;
    unsigned int r = (v.u + 0x7FFFu + ((v.u >> 16) & 1u)) >> 16;  // RNE
    return (ushort_t)r;
}

__device__ __forceinline__ void gload_lds16(const ushort_t* g, ushort_t* l) {
    __builtin_amdgcn_global_load_lds(
        (const __attribute__((address_space(1))) void*)g,
        (__attribute__((address_space(3))) void*)l,
        16, 0, 0);
}

// ---------------- tiled transpose + convert: in [E][R][C] f32 -> out [E][C][R] bf16 ----
__global__ void transpose_conv_kernel(
    const float* __restrict__ in, ushort_t* __restrict__ out, int R, int C)
{
    __shared__ float tile[32][33];
    const int e = blockIdx.z;
    const float* I = in + (size_t)e * R * C;
    ushort_t*    O = out + (size_t)e * R * C;
    const int c0 = blockIdx.x * 32, r0 = blockIdx.y * 32;
    const int tx = threadIdx.x, ty = threadIdx.y;   // 32 x 8
#pragma unroll
    for (int j = 0; j < 32; j += 8)
        tile[ty + j][tx] = I[(size_t)(r0 + ty + j) * C + (c0 + tx)];
    __syncthreads();
#pragma unroll
    for (int j = 0; j < 32; j += 8)
        O[(size_t)(c0 + ty + j) * R + (r0 + tx)] = f2bf(tile[tx][ty + j]);
}

// ---------------- router: 128 blocks x 64 tokens; ballot ranking, 8 atomics/blk ----
__global__ __launch_bounds__(256) void router_kernel(
    const float* __restrict__ x, const float* __restrict__ Wr, const float* __restrict__ br,
    int* __restrict__ cnt, int* __restrict__ tok_list, float* __restrict__ w_list)
{
    __shared__ int   se0[64], se1[64];
    __shared__ float sw0[64], sw1[64];

    const int wid  = threadIdx.x >> 6;
    const int lane = threadIdx.x & 63;
    const int tblk = blockIdx.x * 64;

    for (int i = 0; i < 16; ++i) {
        const int li = wid * 16 + i;            // token slot in block
        const int t  = tblk + li;
        const float* xr = x + (size_t)t * DIM;

        float acc[NE];
#pragma unroll
        for (int e = 0; e < NE; ++e) acc[e] = 0.f;
        for (int d = lane; d < DIM; d += 64) {
            float xv = xr[d];
            const float4* w4 = reinterpret_cast<const float4*>(Wr + (size_t)d * NE);
            float4 w0 = w4[0], w1 = w4[1];
            acc[0] += xv * w0.x; acc[1] += xv * w0.y; acc[2] += xv * w0.z; acc[3] += xv * w0.w;
            acc[4] += xv * w1.x; acc[5] += xv * w1.y; acc[6] += xv * w1.z; acc[7] += xv * w1.w;
        }
#pragma unroll
        for (int e = 0; e < NE; ++e) {
            for (int off = 32; off > 0; off >>= 1)
                acc[e] += __shfl_down(acc[e], off, 64);
        }
        if (lane == 0) {
            float l[NE];
#pragma unroll
            for (int e = 0; e < NE; ++e) l[e] = acc[e] + br[e];
            float mx = l[0];
#pragma unroll
            for (int e = 1; e < NE; ++e) mx = fmaxf(mx, l[e]);
            float p[NE], s = 0.f;
#pragma unroll
            for (int e = 0; e < NE; ++e) { p[e] = expf(l[e] - mx); s += p[e]; }
            float inv = 1.f / s;
            // top-2, lowest-index-on-tie (strict >) to match jax.lax.top_k
            int e0 = 0;
#pragma unroll
            for (int e = 1; e < NE; ++e) if (l[e] > l[e0]) e0 = e;
            int e1 = (e0 == 0) ? 1 : 0;
#pragma unroll
            for (int e = 0; e < NE; ++e) if (e != e0 && l[e] > l[e1]) e1 = e;
            se0[li] = e0; sw0[li] = p[e0] * inv;
            se1[li] = e1; sw1[li] = p[e1] * inv;
        }
    }
    __syncthreads();

    // wave 0: rank 64 tokens x 2 slots per expert, reserve ranges, scatter
    if (threadIdx.x < 64) {
        const int t  = tblk + lane;
        const int e0 = se0[lane], e1 = se1[lane];
        const unsigned long long below = ((unsigned long long)1 << lane) - 1;
        int p0 = 0, p1 = 0;
#pragma unroll
        for (int e = 0; e < NE; ++e) {
            unsigned long long m0 = __ballot(e0 == e);
            unsigned long long m1 = __ballot(e1 == e);
            int c = __popcll(m0) + __popcll(m1);
            int b = 0;
            if (lane == e && c) b = atomicAdd(&cnt[e], c);
            b = __shfl(b, e, 64);
            if (e0 == e) p0 = b + __popcll(m0 & below);
            if (e1 == e) p1 = b + __popcll(m0) + __popcll(m1 & below);
        }
        tok_list[e0 * N_TOK + p0] = t;  w_list[e0 * N_TOK + p0] = sw0[lane];
        tok_list[e1 * N_TOK + p1] = t;  w_list[e1 * N_TOK + p1] = sw1[lane];
    }
}

__global__ void scan_kernel(const int* __restrict__ cnt, int* __restrict__ offs)
{
    if (threadIdx.x == 0 && blockIdx.x == 0) {
        int s = 0;
        for (int e = 0; e < NE; ++e) { offs[e] = s; s += cnt[e]; }
        offs[NE] = s;
    }
}

// ---------------- gather+convert A: xpack[row] = bf16(x[tok(row)]), contiguous ----
__global__ __launch_bounds__(256) void gather_a_kernel(
    const float* __restrict__ x, const int* __restrict__ offs,
    const int* __restrict__ tok_list, ushort_t* __restrict__ xpack)
{
    const int c   = blockIdx.x * 256 + threadIdx.x;   // one 8-elem chunk
    const int row = c >> 7;                           // 128 chunks per row
    int e = 0;
#pragma unroll
    for (int k = 1; k < NE; ++k) e += (row >= offs[k]);
    const int tok = tok_list[e * N_TOK + (row - offs[e])];
    const int d0  = (c & 127) << 3;
    const float* src = x + ((size_t)tok << 10) + d0;
    float4 a = *reinterpret_cast<const float4*>(src);
    float4 b = *reinterpret_cast<const float4*>(src + 4);
    u16x8 o;
    o[0] = f2bf(a.x); o[1] = f2bf(a.y); o[2] = f2bf(a.z); o[3] = f2bf(a.w);
    o[4] = f2bf(b.x); o[5] = f2bf(b.y); o[6] = f2bf(b.z); o[7] = f2bf(b.w);
    *reinterpret_cast<u16x8*>(xpack + ((size_t)row << 10) + d0) = o;
}

// ------- grouped GEMM, 256x256 tile, BK=64, 8 waves (2x4), per-wave 128x64 -------
// LDS: STATIC 2 buffers (As0/Bs0, As1/Bs1), [row 0..255][slot 0..7][8 bf16];
// slot s of row r holds global chunk (s ^ (r&7)) (involution; read same XOR).
// K-loop (unrolled x2): STAGE(t+1->buf1); COMPUTE(buf0); vm0; bar;
//                       STAGE(t+2->buf0); COMPUTE(buf1); vm0; bar.
// MODE 0: A = xpack (packed rows), epilogue bias+GELU -> h (bf16)
// MODE 1: A = h rows (contiguous), epilogue bias, * w, atomicAdd -> out
template <int MODE>
__global__ __launch_bounds__(512, 1) void moe_gemm_kernel(
    const ushort_t* __restrict__ A,     // packed rows [16384(+slack)][K]
    const ushort_t* __restrict__ Bt,    // [NE][NCOL][K] bf16 (K contiguous)
    const float*    __restrict__ bias,  // [NE][NCOL]
    const int*      __restrict__ cnt,
    const int*      __restrict__ offs,
    const int*      __restrict__ tok_list,
    const float*    __restrict__ w_list,
    ushort_t*       __restrict__ hout,
    float*          __restrict__ out,
    int K, int NCOL)
{
    const int e = blockIdx.z;
    const int cnt_e = cnt[e];

    const int wg = blockIdx.x;        // no swizzle: balanced XCDs, same-panel
    const int mb = wg & 63;           // blocks share an XCD via dispatch order
    const int nb = wg >> 6;

    const int m0 = mb * 256;
    if (m0 >= cnt_e) return;          // early-exit unused tiles
    const int n0 = nb * 256;
    const int offs_e = offs[e];

    __shared__ ushort_t As0[256 * 64];
    __shared__ ushort_t Bs0[256 * 64];
    __shared__ ushort_t As1[256 * 64];
    __shared__ ushort_t Bs1[256 * 64];

    const int tid = threadIdx.x;

    // staging sources: c = tid + 512*j; row=c>>3, slot=c&7,
    // global chunk = slot ^ (row&7) (inverse swizzle at the source)
    size_t asrc[4], bsrc[4];
#pragma unroll
    for (int j = 0; j < 4; ++j) {
        int c = tid + 512 * j;
        int row = c >> 3;
        int gch = (c & 7) ^ (row & 7);
        int entry = m0 + row;
        size_t arow;
        if (MODE == 0) {
            arow = (entry < cnt_e) ? (size_t)(offs_e + entry) * K : 0;
        } else {
            arow = (size_t)(offs_e + entry) * K;   // slack rows allocated in h
        }
        asrc[j] = arow + (size_t)gch * 8;
        int col = n0 + row;
        bsrc[j] = ((size_t)e * NCOL + col) * K + (size_t)gch * 8;
    }

    f32x4 acc[8][4];
#pragma unroll
    for (int m = 0; m < 8; ++m)
#pragma unroll
        for (int n = 0; n < 4; ++n)
            acc[m][n] = (f32x4){0.f, 0.f, 0.f, 0.f};

    const int lane = tid & 63;
    const int wid  = tid >> 6;
    const int wr = (wid >> 2) * 128;   // wave rows [wr, wr+128)
    const int wc = (wid & 3) * 64;     // wave cols [wc, wc+64)
    const int la = lane & 15;
    const int kc = lane >> 4;          // k-chunk within 32-k slice

    auto STAGE = [&](int t, ushort_t* Ad, ushort_t* Bd) {
        const int k0 = t * 64;
#pragma unroll
        for (int j = 0; j < 4; ++j) {
            gload_lds16(A  + asrc[j] + k0, &Ad[(tid + 512 * j) * 8]);
            gload_lds16(Bt + bsrc[j] + k0, &Bd[(tid + 512 * j) * 8]);
        }
    };

    auto COMPUTE = [&](const ushort_t* Ad, const ushort_t* Bd) {
#pragma unroll
        for (int s = 0; s < 2; ++s) {
            bf16x8 af[8], bfr[4];
#pragma unroll
            for (int m = 0; m < 8; ++m) {
                int r = wr + m * 16 + la;
                af[m] = *reinterpret_cast<const bf16x8*>(
                    &Ad[(r * 8 + ((s * 4 + kc) ^ (r & 7))) * 8]);
            }
#pragma unroll
            for (int n = 0; n < 4; ++n) {
                int ccol = wc + n * 16 + la;
                bfr[n] = *reinterpret_cast<const bf16x8*>(
                    &Bd[(ccol * 8 + ((s * 4 + kc) ^ (ccol & 7))) * 8]);
            }
#pragma unroll
            for (int m = 0; m < 8; ++m)
#pragma unroll
                for (int n = 0; n < 4; ++n)
                    acc[m][n] = __builtin_amdgcn_mfma_f32_16x16x32_bf16(
                        af[m], bfr[n], acc[m][n], 0, 0, 0);
        }
    };

    const int nt = K / 64;            // 16 or 32: always even
    STAGE(0, As0, Bs0);
    asm volatile("s_waitcnt vmcnt(0)" ::: "memory");
    __builtin_amdgcn_s_barrier();
    for (int t = 0; t < nt; t += 2) {
        STAGE(t + 1, As1, Bs1);       // issue early: hides under COMPUTE(buf0)
        COMPUTE(As0, Bs0);
        asm volatile("s_waitcnt vmcnt(0)" ::: "memory");
        __builtin_amdgcn_s_barrier();
        if (t + 2 < nt) STAGE(t + 2, As0, Bs0);
        COMPUTE(As1, Bs1);
        asm volatile("s_waitcnt vmcnt(0)" ::: "memory");
        __builtin_amdgcn_s_barrier();
    }

    // epilogue: C/D layout col = lane&15, row = (lane>>4)*4 + j (HW-verified)
#pragma unroll
    for (int m = 0; m < 8; ++m) {
        int rbase = wr + m * 16 + (lane >> 4) * 4;
#pragma unroll
        for (int n = 0; n < 4; ++n) {
            int gcol = n0 + wc + n * 16 + la;
            float bi = bias[(size_t)e * NCOL + gcol];
#pragma unroll
            for (int jj = 0; jj < 4; ++jj) {
                int entry = m0 + rbase + jj;
                if (entry < cnt_e) {
                    float v = acc[m][n][jj] + bi;
                    if (MODE == 0) {
                        // jax.nn.gelu approximate=True (tanh form)
                        float u = 0.7978845608028654f * (v + 0.044715f * v * v * v);
                        float g = 0.5f * v * (1.f + tanhf(u));
                        hout[(size_t)(offs_e + entry) * NCOL + gcol] = f2bf(g);
                    } else {
                        int tok  = tok_list[e * N_TOK + entry];
                        float w  = w_list  [e * N_TOK + entry];
                        atomicAdd(&out[(size_t)tok * NCOL + gcol], w * v);
                    }
                }
            }
        }
    }
}

extern "C" void kernel_launch(void* const* d_in, const int* in_sizes, int n_in,
                              void* d_out, int out_size, void* d_ws, size_t ws_size,
                              hipStream_t stream)
{
    const float* x  = (const float*)d_in[0];
    const float* Wr = (const float*)d_in[1];
    const float* br = (const float*)d_in[2];
    const float* W1 = (const float*)d_in[3];
    const float* b1 = (const float*)d_in[4];
    const float* W2 = (const float*)d_in[5];
    const float* b2 = (const float*)d_in[6];
    float* out = (float*)d_out;

    // workspace layout (~161 MB total)
    char* ws = (char*)d_ws;
    size_t off = 0;
    auto alloc = [&](size_t bytes) -> void* {
        void* p = ws + off;
        off = (off + bytes + 255) & ~(size_t)255;
        return p;
    };
    ushort_t* w1t = (ushort_t*)alloc((size_t)NE * DIM * FF * 2);          // 32 MB  [E][F][D]
    ushort_t* w2t = (ushort_t*)alloc((size_t)NE * DIM * FF * 2);          // 32 MB  [E][D][F]
    ushort_t* xpack = (ushort_t*)alloc((size_t)2 * N_TOK * DIM * 2);      // 32 MB packed A
    ushort_t* h   = (ushort_t*)alloc(((size_t)2 * N_TOK + 256) * FF * 2); // 65 MB (+slack rows)
    int*      cnt = (int*)alloc(NE * sizeof(int));
    int*      offs= (int*)alloc((NE + 1) * sizeof(int));
    int*   tok_list = (int*)alloc((size_t)NE * N_TOK * sizeof(int));
    float* w_list   = (float*)alloc((size_t)NE * N_TOK * sizeof(float));
    (void)ws_size; (void)in_sizes; (void)n_in;

    hipMemsetAsync(out, 0, (size_t)out_size * sizeof(float), stream);
    hipMemsetAsync(cnt, 0, NE * sizeof(int), stream);

    transpose_conv_kernel<<<dim3(FF / 32, DIM / 32, NE), dim3(32, 8), 0, stream>>>(W1, w1t, DIM, FF);
    transpose_conv_kernel<<<dim3(DIM / 32, FF / 32, NE), dim3(32, 8), 0, stream>>>(W2, w2t, FF, DIM);
    router_kernel<<<N_TOK / 64, 256, 0, stream>>>(x, Wr, br, cnt, tok_list, w_list);
    scan_kernel<<<1, 64, 0, stream>>>(cnt, offs);
    gather_a_kernel<<<(2 * N_TOK * DIM) / (8 * 256), 256, 0, stream>>>(x, offs, tok_list, xpack);

    moe_gemm_kernel<0><<<dim3(64 * (FF / 256), 1, NE), 512, 0, stream>>>(
        xpack, w1t, b1, cnt, offs, tok_list, w_list, h, nullptr, DIM, FF);
    moe_gemm_kernel<1><<<dim3(64 * (DIM / 256), 1, NE), 512, 0, stream>>>(
        h, w2t, b2, cnt, offs, tok_list, w_list, nullptr, out, FF, DIM);
}

// Round 10
// 504.563 us; speedup vs baseline: 2.2384x; 2.2384x over previous
//
#include <hip/hip_runtime.h>
#include <hip/hip_bf16.h>

// MoE top-2 of 8 experts. N=8192 tokens, D=1024, F=2048.
// R10: persistent-CTA grouped GEMM. Inner K-loop/staging/epilogue are R7's
//      measured-best (128x128, BK=32, 3 LDS bufs, vmcnt(4);barrier;STAGE(t+2);
//      COMPUTE(t)). NEW: exactly 768 blocks (3/CU, all resident), grid-striding
//      a live-tile table built by scan (no dead dispatches, no rounds);
//      mt-major tile order + bijective XCD chunking (per-XCD working set ~L2,
//      per-block B-panel constant); setprio around MFMA; vectorized transpose.

#define N_TOK 8192
#define DIM   1024
#define FF    2048
#define NE    8

typedef unsigned short ushort_t;
typedef __bf16 bf16x8 __attribute__((ext_vector_type(8)));
typedef float  f32x4  __attribute__((ext_vector_type(4)));
typedef unsigned short u16x8 __attribute__((ext_vector_type(8)));

__device__ __forceinline__ ushort_t f2bf(float f) {
    union { float f; unsigned int u; } v; v.f = f;
    unsigned int r = (v.u + 0x7FFFu + ((v.u >> 16) & 1u)) >> 16;  // RNE
    return (ushort_t)r;
}

__device__ __forceinline__ void gload_lds16(const ushort_t* g, ushort_t* l) {
    __builtin_amdgcn_global_load_lds(
        (const __attribute__((address_space(1))) void*)g,
        (__attribute__((address_space(3))) void*)l,
        16, 0, 0);
}

// ---------------- tiled transpose + convert: in [E][R][C] f32 -> out [E][C][R] bf16 ----
// 64x64 tile, 256 threads; float4 loads, ushort8 stores (both 16B/lane).
__global__ __launch_bounds__(256) void transpose_conv_kernel(
    const float* __restrict__ in, ushort_t* __restrict__ out, int R, int C)
{
    __shared__ float tile[64][68];   // stride 68: 16B-aligned float4 rows, banks spread
    const int e = blockIdx.z;
    const float* I = in + (size_t)e * R * C;
    ushort_t*    O = out + (size_t)e * R * C;
    const int c0 = blockIdx.x * 64, r0 = blockIdx.y * 64;
    const int tid = threadIdx.x;
#pragma unroll
    for (int j = 0; j < 4; ++j) {
        int row = j * 16 + (tid >> 4);
        int col = (tid & 15) * 4;
        float4 v = *reinterpret_cast<const float4*>(&I[(size_t)(r0 + row) * C + c0 + col]);
        *reinterpret_cast<float4*>(&tile[row][col]) = v;
    }
    __syncthreads();
#pragma unroll
    for (int j = 0; j < 2; ++j) {
        int orow = j * 32 + (tid >> 3);      // output row = input col
        int k0   = (tid & 7) * 8;            // 8 input rows -> 8 out elems
        u16x8 o;
#pragma unroll
        for (int k = 0; k < 8; ++k) o[k] = f2bf(tile[k0 + k][orow]);
        *reinterpret_cast<u16x8*>(&O[(size_t)(c0 + orow) * R + r0 + k0]) = o;
    }
}

// ---------------- router: 128 blocks x 64 tokens; ballot ranking, 8 atomics/blk ----
__global__ __launch_bounds__(256) void router_kernel(
    const float* __restrict__ x, const float* __restrict__ Wr, const float* __restrict__ br,
    int* __restrict__ cnt, int* __restrict__ tok_list, float* __restrict__ w_list)
{
    __shared__ int   se0[64], se1[64];
    __shared__ float sw0[64], sw1[64];

    const int wid  = threadIdx.x >> 6;
    const int lane = threadIdx.x & 63;
    const int tblk = blockIdx.x * 64;

    for (int i = 0; i < 16; ++i) {
        const int li = wid * 16 + i;            // token slot in block
        const int t  = tblk + li;
        const float* xr = x + (size_t)t * DIM;

        float acc[NE];
#pragma unroll
        for (int e = 0; e < NE; ++e) acc[e] = 0.f;
        for (int d = lane; d < DIM; d += 64) {
            float xv = xr[d];
            const float4* w4 = reinterpret_cast<const float4*>(Wr + (size_t)d * NE);
            float4 w0 = w4[0], w1 = w4[1];
            acc[0] += xv * w0.x; acc[1] += xv * w0.y; acc[2] += xv * w0.z; acc[3] += xv * w0.w;
            acc[4] += xv * w1.x; acc[5] += xv * w1.y; acc[6] += xv * w1.z; acc[7] += xv * w1.w;
        }
#pragma unroll
        for (int e = 0; e < NE; ++e) {
            for (int off = 32; off > 0; off >>= 1)
                acc[e] += __shfl_down(acc[e], off, 64);
        }
        if (lane == 0) {
            float l[NE];
#pragma unroll
            for (int e = 0; e < NE; ++e) l[e] = acc[e] + br[e];
            float mx = l[0];
#pragma unroll
            for (int e = 1; e < NE; ++e) mx = fmaxf(mx, l[e]);
            float p[NE], s = 0.f;
#pragma unroll
            for (int e = 0; e < NE; ++e) { p[e] = expf(l[e] - mx); s += p[e]; }
            float inv = 1.f / s;
            // top-2, lowest-index-on-tie (strict >) to match jax.lax.top_k
            int e0 = 0;
#pragma unroll
            for (int e = 1; e < NE; ++e) if (l[e] > l[e0]) e0 = e;
            int e1 = (e0 == 0) ? 1 : 0;
#pragma unroll
            for (int e = 0; e < NE; ++e) if (e != e0 && l[e] > l[e1]) e1 = e;
            se0[li] = e0; sw0[li] = p[e0] * inv;
            se1[li] = e1; sw1[li] = p[e1] * inv;
        }
    }
    __syncthreads();

    // wave 0: rank 64 tokens x 2 slots per expert, reserve ranges, scatter
    if (threadIdx.x < 64) {
        const int t  = tblk + lane;
        const int e0 = se0[lane], e1 = se1[lane];
        const unsigned long long below = ((unsigned long long)1 << lane) - 1;
        int p0 = 0, p1 = 0;
#pragma unroll
        for (int e = 0; e < NE; ++e) {
            unsigned long long m0 = __ballot(e0 == e);
            unsigned long long m1 = __ballot(e1 == e);
            int c = __popcll(m0) + __popcll(m1);
            int b = 0;
            if (lane == e && c) b = atomicAdd(&cnt[e], c);
            b = __shfl(b, e, 64);
            if (e0 == e) p0 = b + __popcll(m0 & below);
            if (e1 == e) p1 = b + __popcll(m0) + __popcll(m1 & below);
        }
        tok_list[e0 * N_TOK + p0] = t;  w_list[e0 * N_TOK + p0] = sw0[lane];
        tok_list[e1 * N_TOK + p1] = t;  w_list[e1 * N_TOK + p1] = sw1[lane];
    }
}

// scan + live-tile table: tile_e/tile_m0 for every 128-row m-tile (<=135)
__global__ void scan_kernel(const int* __restrict__ cnt, int* __restrict__ offs,
                            int* __restrict__ tile_e, int* __restrict__ tile_m0,
                            int* __restrict__ meta)
{
    if (threadIdx.x == 0 && blockIdx.x == 0) {
        int s = 0;
        for (int e = 0; e < NE; ++e) { offs[e] = s; s += cnt[e]; }
        offs[NE] = s;
        int nt = 0;
        for (int e = 0; e < NE; ++e)
            for (int m0 = 0; m0 < cnt[e]; m0 += 128) {
                tile_e[nt] = e; tile_m0[nt] = m0; ++nt;
            }
        meta[0] = nt;
    }
}

// ---------------- gather+convert A: xpack[row] = bf16(x[tok(row)]), contiguous ----
__global__ __launch_bounds__(256) void gather_a_kernel(
    const float* __restrict__ x, const int* __restrict__ offs,
    const int* __restrict__ tok_list, ushort_t* __restrict__ xpack)
{
    const int c   = blockIdx.x * 256 + threadIdx.x;   // one 8-elem chunk
    const int row = c >> 7;                           // 128 chunks per row
    int e = 0;
#pragma unroll
    for (int k = 1; k < NE; ++k) e += (row >= offs[k]);
    const int tok = tok_list[e * N_TOK + (row - offs[e])];
    const int d0  = (c & 127) << 3;
    const float* src = x + ((size_t)tok << 10) + d0;
    float4 a = *reinterpret_cast<const float4*>(src);
    float4 b = *reinterpret_cast<const float4*>(src + 4);
    u16x8 o;
    o[0] = f2bf(a.x); o[1] = f2bf(a.y); o[2] = f2bf(a.z); o[3] = f2bf(a.w);
    o[4] = f2bf(b.x); o[5] = f2bf(b.y); o[6] = f2bf(b.z); o[7] = f2bf(b.w);
    *reinterpret_cast<u16x8*>(xpack + ((size_t)row << 10) + d0) = o;
}

// ------- persistent grouped GEMM, 128x128 tile, BK=32, 4 waves, acc 4x4 -------
// 768 blocks (3/CU, all resident). Block b owns XCD chunk b&7 of the live-tile
// space (L = nmt*NB tiles, mt-major: tau = mt*NB + nb), striding by 96.
// Inner loop EXACTLY R7: 3 LDS bufs, vmcnt(4);barrier;STAGE(t+2);COMPUTE(t).
// MODE 0: A = xpack, epilogue bias+GELU -> h.  MODE 1: A = h, * w, atomicAdd.
template <int MODE>
__global__ __launch_bounds__(256) void moe_gemm_kernel(
    const ushort_t* __restrict__ A,     // packed rows [16384(+slack)][K]
    const ushort_t* __restrict__ Bt,    // [NE][NCOL][K] bf16 (K contiguous)
    const float*    __restrict__ bias,  // [NE][NCOL]
    const int*      __restrict__ cnt,
    const int*      __restrict__ offs,
    const int*      __restrict__ tok_list,
    const float*    __restrict__ w_list,
    const int*      __restrict__ tile_e,
    const int*      __restrict__ tile_m0,
    const int*      __restrict__ meta,
    ushort_t*       __restrict__ hout,
    float*          __restrict__ out,
    int K, int NCOL)
{
    const int nmt = meta[0];
    const int NB  = NCOL >> 7;
    const int L   = nmt * NB;

    const int xcd = blockIdx.x & 7;
    const int q = L >> 3, r = L & 7;
    const int cstart = (xcd < r) ? xcd * (q + 1) : r * (q + 1) + (xcd - r) * q;
    const int clen   = (xcd < r) ? q + 1 : q;

    __shared__ ushort_t As[3][128 * 32];
    __shared__ ushort_t Bs[3][128 * 32];

    const int tid  = threadIdx.x;
    const int lane = tid & 63;
    const int wid  = tid >> 6;
    const int wr = (wid >> 1) * 64;
    const int wc = (wid & 1) * 64;
    const int la = lane & 15;
    const int kc = lane >> 4;

    for (int i = blockIdx.x >> 3; i < clen; i += 96) {
        const int tau = cstart + i;
        const int nb  = tau & (NB - 1);       // NB is 8 or 16 (pow2)
        const int mt  = tau >> (NB == 16 ? 4 : 3);
        const int e   = tile_e[mt];
        const int m0  = tile_m0[mt];
        const int cnt_e  = cnt[e];
        const int offs_e = offs[e];
        const int n0  = nb * 128;

        __syncthreads();   // prior tile's LDS readers done before restaging

        // per-thread staging sources (R7 scheme: row=c>>2, chunk=(c&3)^((row>>1)&3))
        size_t asrc[2], bsrc[2];
#pragma unroll
        for (int j = 0; j < 2; ++j) {
            int c = tid + 256 * j;
            int row   = c >> 2;
            int chunk = (c & 3) ^ ((row >> 1) & 3);
            int entry = m0 + row;
            size_t arow;
            if (MODE == 0) {
                arow = (entry < cnt_e) ? (size_t)(offs_e + entry) * K : 0;
            } else {
                arow = (size_t)(offs_e + entry) * K;   // slack rows in h
            }
            asrc[j] = arow + (size_t)chunk * 8;
            int col = n0 + row;
            bsrc[j] = ((size_t)e * NCOL + col) * K + (size_t)chunk * 8;
        }

        f32x4 acc[4][4];
#pragma unroll
        for (int m = 0; m < 4; ++m)
#pragma unroll
            for (int n = 0; n < 4; ++n)
                acc[m][n] = (f32x4){0.f, 0.f, 0.f, 0.f};

        auto STAGE = [&](int t, int b) {
            int k0 = t * 32;
#pragma unroll
            for (int j = 0; j < 2; ++j) {
                gload_lds16(A  + asrc[j] + k0, &As[b][(tid + 256 * j) * 8]);
                gload_lds16(Bt + bsrc[j] + k0, &Bs[b][(tid + 256 * j) * 8]);
            }
        };

        auto COMPUTE = [&](int b) {
            bf16x8 af[4], bfr[4];
#pragma unroll
            for (int m = 0; m < 4; ++m) {
                int rr = wr + m * 16 + la;
                af[m] = *reinterpret_cast<const bf16x8*>(&As[b][(rr * 4 + (kc ^ ((rr >> 1) & 3))) * 8]);
            }
#pragma unroll
            for (int n = 0; n < 4; ++n) {
                int rr = wc + n * 16 + la;
                bfr[n] = *reinterpret_cast<const bf16x8*>(&Bs[b][(rr * 4 + (kc ^ ((rr >> 1) & 3))) * 8]);
            }
            __builtin_amdgcn_s_setprio(1);
#pragma unroll
            for (int m = 0; m < 4; ++m)
#pragma unroll
                for (int n = 0; n < 4; ++n)
                    acc[m][n] = __builtin_amdgcn_mfma_f32_16x16x32_bf16(af[m], bfr[n], acc[m][n], 0, 0, 0);
            __builtin_amdgcn_s_setprio(0);
        };

        const int nk = K / 32;
        STAGE(0, 0);
        STAGE(1, 1);
        for (int t = 0; t < nk - 1; ++t) {
            asm volatile("s_waitcnt vmcnt(4)" ::: "memory");
            __builtin_amdgcn_s_barrier();
            if (t + 2 < nk) STAGE(t + 2, (t + 2) % 3);
            COMPUTE(t % 3);
        }
        asm volatile("s_waitcnt vmcnt(0)" ::: "memory");
        __builtin_amdgcn_s_barrier();
        COMPUTE((nk - 1) % 3);

        // epilogue: C/D layout col = lane&15, row = (lane>>4)*4 + j (HW-verified)
#pragma unroll
        for (int m = 0; m < 4; ++m) {
            int rbase = wr + m * 16 + (lane >> 4) * 4;
#pragma unroll
            for (int n = 0; n < 4; ++n) {
                int gcol = n0 + wc + n * 16 + la;
                float bi = bias[(size_t)e * NCOL + gcol];
#pragma unroll
                for (int jj = 0; jj < 4; ++jj) {
                    int entry = m0 + rbase + jj;
                    if (entry < cnt_e) {
                        float v = acc[m][n][jj] + bi;
                        if (MODE == 0) {
                            // jax.nn.gelu approximate=True (tanh form)
                            float u = 0.7978845608028654f * (v + 0.044715f * v * v * v);
                            float g = 0.5f * v * (1.f + tanhf(u));
                            hout[(size_t)(offs_e + entry) * NCOL + gcol] = f2bf(g);
                        } else {
                            int tok  = tok_list[e * N_TOK + entry];
                            float w  = w_list  [e * N_TOK + entry];
                            atomicAdd(&out[(size_t)tok * NCOL + gcol], w * v);
                        }
                    }
                }
            }
        }
    }
}

extern "C" void kernel_launch(void* const* d_in, const int* in_sizes, int n_in,
                              void* d_out, int out_size, void* d_ws, size_t ws_size,
                              hipStream_t stream)
{
    const float* x  = (const float*)d_in[0];
    const float* Wr = (const float*)d_in[1];
    const float* br = (const float*)d_in[2];
    const float* W1 = (const float*)d_in[3];
    const float* b1 = (const float*)d_in[4];
    const float* W2 = (const float*)d_in[5];
    const float* b2 = (const float*)d_in[6];
    float* out = (float*)d_out;

    // workspace layout (~161 MB total)
    char* ws = (char*)d_ws;
    size_t off = 0;
    auto alloc = [&](size_t bytes) -> void* {
        void* p = ws + off;
        off = (off + bytes + 255) & ~(size_t)255;
        return p;
    };
    ushort_t* w1t = (ushort_t*)alloc((size_t)NE * DIM * FF * 2);          // 32 MB  [E][F][D]
    ushort_t* w2t = (ushort_t*)alloc((size_t)NE * DIM * FF * 2);          // 32 MB  [E][D][F]
    ushort_t* xpack = (ushort_t*)alloc((size_t)2 * N_TOK * DIM * 2);      // 32 MB packed A
    ushort_t* h   = (ushort_t*)alloc(((size_t)2 * N_TOK + 256) * FF * 2); // 65 MB (+slack rows)
    int*      cnt = (int*)alloc(NE * sizeof(int));
    int*      offs= (int*)alloc((NE + 1) * sizeof(int));
    int*   tok_list = (int*)alloc((size_t)NE * N_TOK * sizeof(int));
    float* w_list   = (float*)alloc((size_t)NE * N_TOK * sizeof(float));
    int*   tile_e   = (int*)alloc(256 * sizeof(int));
    int*   tile_m0  = (int*)alloc(256 * sizeof(int));
    int*   meta     = (int*)alloc(16 * sizeof(int));
    (void)ws_size; (void)in_sizes; (void)n_in;

    hipMemsetAsync(out, 0, (size_t)out_size * sizeof(float), stream);
    hipMemsetAsync(cnt, 0, NE * sizeof(int), stream);

    transpose_conv_kernel<<<dim3(FF / 64, DIM / 64, NE), 256, 0, stream>>>(W1, w1t, DIM, FF);
    transpose_conv_kernel<<<dim3(DIM / 64, FF / 64, NE), 256, 0, stream>>>(W2, w2t, FF, DIM);
    router_kernel<<<N_TOK / 64, 256, 0, stream>>>(x, Wr, br, cnt, tok_list, w_list);
    scan_kernel<<<1, 64, 0, stream>>>(cnt, offs, tile_e, tile_m0, meta);
    gather_a_kernel<<<(2 * N_TOK * DIM) / (8 * 256), 256, 0, stream>>>(x, offs, tok_list, xpack);

    moe_gemm_kernel<0><<<768, 256, 0, stream>>>(
        xpack, w1t, b1, cnt, offs, tok_list, w_list, tile_e, tile_m0, meta, h, nullptr, DIM, FF);
    moe_gemm_kernel<1><<<768, 256, 0, stream>>>(
        h, w2t, b2, cnt, offs, tok_list, w_list, tile_e, tile_m0, meta, nullptr, out, FF, DIM);
}

// Round 11
// 453.899 us; speedup vs baseline: 2.4882x; 1.1116x over previous
//
#include <hip/hip_runtime.h>
#include <hip/hip_bf16.h>

// MoE top-2 of 8 experts. N=8192 tokens, D=1024, F=2048.
// R11: persistent grouped GEMM keeps R10's mt-major XCD-chunked tile walk and
//      R7 inner loop; changes: (1) 8 waves/block at 128x128 (2x4 wave grid,
//      per-wave 64x32, vmcnt(2)) -> 24 waves/CU latency hiding;
//      (2) GEMM2 split-K=2 -> L=2112 for both GEMMs (tail 45%->9%);
//      (3) gather pass deleted (in-GEMM tok_list gather, proven in R4),
//      convert_x restored; GELU tanh via exp2 identity.

#define N_TOK 8192
#define DIM   1024
#define FF    2048
#define NE    8

typedef unsigned short ushort_t;
typedef __bf16 bf16x8 __attribute__((ext_vector_type(8)));
typedef float  f32x4  __attribute__((ext_vector_type(4)));
typedef unsigned short u16x8 __attribute__((ext_vector_type(8)));

__device__ __forceinline__ ushort_t f2bf(float f) {
    union { float f; unsigned int u; } v; v.f = f;
    unsigned int r = (v.u + 0x7FFFu + ((v.u >> 16) & 1u)) >> 16;  // RNE
    return (ushort_t)r;
}

__device__ __forceinline__ void gload_lds16(const ushort_t* g, ushort_t* l) {
    __builtin_amdgcn_global_load_lds(
        (const __attribute__((address_space(1))) void*)g,
        (__attribute__((address_space(3))) void*)l,
        16, 0, 0);
}

// ---------------- convert x fp32 -> bf16 ----------------
__global__ __launch_bounds__(256) void convert_x_kernel(
    const float* __restrict__ x, ushort_t* __restrict__ xb)
{
    size_t i = ((size_t)blockIdx.x * 256 + threadIdx.x) * 8;
    float4 a = *reinterpret_cast<const float4*>(x + i);
    float4 b = *reinterpret_cast<const float4*>(x + i + 4);
    u16x8 o;
    o[0] = f2bf(a.x); o[1] = f2bf(a.y); o[2] = f2bf(a.z); o[3] = f2bf(a.w);
    o[4] = f2bf(b.x); o[5] = f2bf(b.y); o[6] = f2bf(b.z); o[7] = f2bf(b.w);
    *reinterpret_cast<u16x8*>(xb + i) = o;
}

// ---------------- tiled transpose + convert: in [E][R][C] f32 -> out [E][C][R] bf16 ----
__global__ __launch_bounds__(256) void transpose_conv_kernel(
    const float* __restrict__ in, ushort_t* __restrict__ out, int R, int C)
{
    __shared__ float tile[64][68];
    const int e = blockIdx.z;
    const float* I = in + (size_t)e * R * C;
    ushort_t*    O = out + (size_t)e * R * C;
    const int c0 = blockIdx.x * 64, r0 = blockIdx.y * 64;
    const int tid = threadIdx.x;
#pragma unroll
    for (int j = 0; j < 4; ++j) {
        int row = j * 16 + (tid >> 4);
        int col = (tid & 15) * 4;
        float4 v = *reinterpret_cast<const float4*>(&I[(size_t)(r0 + row) * C + c0 + col]);
        *reinterpret_cast<float4*>(&tile[row][col]) = v;
    }
    __syncthreads();
#pragma unroll
    for (int j = 0; j < 2; ++j) {
        int orow = j * 32 + (tid >> 3);
        int k0   = (tid & 7) * 8;
        u16x8 o;
#pragma unroll
        for (int k = 0; k < 8; ++k) o[k] = f2bf(tile[k0 + k][orow]);
        *reinterpret_cast<u16x8*>(&O[(size_t)(c0 + orow) * R + r0 + k0]) = o;
    }
}

// ---------------- router: 128 blocks x 64 tokens; ballot ranking, 8 atomics/blk ----
__global__ __launch_bounds__(256) void router_kernel(
    const float* __restrict__ x, const float* __restrict__ Wr, const float* __restrict__ br,
    int* __restrict__ cnt, int* __restrict__ tok_list, float* __restrict__ w_list)
{
    __shared__ int   se0[64], se1[64];
    __shared__ float sw0[64], sw1[64];

    const int wid  = threadIdx.x >> 6;
    const int lane = threadIdx.x & 63;
    const int tblk = blockIdx.x * 64;

    for (int i = 0; i < 16; ++i) {
        const int li = wid * 16 + i;
        const int t  = tblk + li;
        const float* xr = x + (size_t)t * DIM;

        float acc[NE];
#pragma unroll
        for (int e = 0; e < NE; ++e) acc[e] = 0.f;
        for (int d = lane; d < DIM; d += 64) {
            float xv = xr[d];
            const float4* w4 = reinterpret_cast<const float4*>(Wr + (size_t)d * NE);
            float4 w0 = w4[0], w1 = w4[1];
            acc[0] += xv * w0.x; acc[1] += xv * w0.y; acc[2] += xv * w0.z; acc[3] += xv * w0.w;
            acc[4] += xv * w1.x; acc[5] += xv * w1.y; acc[6] += xv * w1.z; acc[7] += xv * w1.w;
        }
#pragma unroll
        for (int e = 0; e < NE; ++e) {
            for (int off = 32; off > 0; off >>= 1)
                acc[e] += __shfl_down(acc[e], off, 64);
        }
        if (lane == 0) {
            float l[NE];
#pragma unroll
            for (int e = 0; e < NE; ++e) l[e] = acc[e] + br[e];
            float mx = l[0];
#pragma unroll
            for (int e = 1; e < NE; ++e) mx = fmaxf(mx, l[e]);
            float p[NE], s = 0.f;
#pragma unroll
            for (int e = 0; e < NE; ++e) { p[e] = expf(l[e] - mx); s += p[e]; }
            float inv = 1.f / s;
            int e0 = 0;
#pragma unroll
            for (int e = 1; e < NE; ++e) if (l[e] > l[e0]) e0 = e;
            int e1 = (e0 == 0) ? 1 : 0;
#pragma unroll
            for (int e = 0; e < NE; ++e) if (e != e0 && l[e] > l[e1]) e1 = e;
            se0[li] = e0; sw0[li] = p[e0] * inv;
            se1[li] = e1; sw1[li] = p[e1] * inv;
        }
    }
    __syncthreads();

    if (threadIdx.x < 64) {
        const int t  = tblk + lane;
        const int e0 = se0[lane], e1 = se1[lane];
        const unsigned long long below = ((unsigned long long)1 << lane) - 1;
        int p0 = 0, p1 = 0;
#pragma unroll
        for (int e = 0; e < NE; ++e) {
            unsigned long long m0 = __ballot(e0 == e);
            unsigned long long m1 = __ballot(e1 == e);
            int c = __popcll(m0) + __popcll(m1);
            int b = 0;
            if (lane == e && c) b = atomicAdd(&cnt[e], c);
            b = __shfl(b, e, 64);
            if (e0 == e) p0 = b + __popcll(m0 & below);
            if (e1 == e) p1 = b + __popcll(m0) + __popcll(m1 & below);
        }
        tok_list[e0 * N_TOK + p0] = t;  w_list[e0 * N_TOK + p0] = sw0[lane];
        tok_list[e1 * N_TOK + p1] = t;  w_list[e1 * N_TOK + p1] = sw1[lane];
    }
}

// scan + live-tile table: tile_e/tile_m0 for every 128-row m-tile (<=136)
__global__ void scan_kernel(const int* __restrict__ cnt, int* __restrict__ offs,
                            int* __restrict__ tile_e, int* __restrict__ tile_m0,
                            int* __restrict__ meta)
{
    if (threadIdx.x == 0 && blockIdx.x == 0) {
        int s = 0;
        for (int e = 0; e < NE; ++e) { offs[e] = s; s += cnt[e]; }
        offs[NE] = s;
        int nt = 0;
        for (int e = 0; e < NE; ++e)
            for (int m0 = 0; m0 < cnt[e]; m0 += 128) {
                tile_e[nt] = e; tile_m0[nt] = m0; ++nt;
            }
        meta[0] = nt;
    }
}

// ------- persistent grouped GEMM, 128x128 tile, BK=32, 8 waves (2x4) -------
// Per-wave 64x32 output (4m x 2n frags, 8 MFMA/step). 768 blocks, 3/CU,
// 24 waves/CU. tau = mt*16 + sub; MODE0: sub=nb (16 n-tiles of FF);
// MODE1: sub = nb*2 + kh (8 n-tiles x split-K2 over K=2048).
// Inner loop = R7: 3 LDS bufs, vmcnt(2);barrier;STAGE(t+2);COMPUTE(t).
// MODE 0: A = xb gathered via tok_list, epilogue bias+GELU -> h (bf16)
// MODE 1: A = h (contiguous), epilogue (kh==0 ? bias:0), * w, atomicAdd -> out
template <int MODE>
__global__ __launch_bounds__(512, 6) void moe_gemm_kernel(
    const ushort_t* __restrict__ A,
    const ushort_t* __restrict__ Bt,    // [NE][NCOL][K] bf16 (K contiguous)
    const float*    __restrict__ bias,  // [NE][NCOL]
    const int*      __restrict__ cnt,
    const int*      __restrict__ offs,
    const int*      __restrict__ tok_list,
    const float*    __restrict__ w_list,
    const int*      __restrict__ tile_e,
    const int*      __restrict__ tile_m0,
    const int*      __restrict__ meta,
    ushort_t*       __restrict__ hout,
    float*          __restrict__ out)
{
    const int K    = (MODE == 0) ? 1024 : 2048;   // full row stride (elems)
    const int NCOL = (MODE == 0) ? 2048 : 1024;

    const int nmt = meta[0];
    const int L   = nmt << 4;                     // 16 sub-tiles per m-tile, both modes

    const int xcd = blockIdx.x & 7;
    const int q = L >> 3, r = L & 7;
    const int cstart = (xcd < r) ? xcd * (q + 1) : r * (q + 1) + (xcd - r) * q;
    const int clen   = (xcd < r) ? q + 1 : q;

    __shared__ ushort_t As[3][128 * 32];
    __shared__ ushort_t Bs[3][128 * 32];

    const int tid  = threadIdx.x;
    const int lane = tid & 63;
    const int wid  = tid >> 6;
    const int wr = (wid >> 2) * 64;    // wave rows [wr, wr+64)
    const int wc = (wid & 3) * 32;     // wave cols [wc, wc+32)
    const int la = lane & 15;
    const int kc = lane >> 4;

    for (int i = blockIdx.x >> 3; i < clen; i += 96) {
        const int tau = cstart + i;
        const int mt  = tau >> 4;
        int nb, kh;
        if (MODE == 0) { nb = tau & 15; kh = 0; }
        else           { kh = tau & 1;  nb = (tau >> 1) & 7; }
        const int e   = tile_e[mt];
        const int m0  = tile_m0[mt];
        const int cnt_e  = cnt[e];
        const int offs_e = offs[e];
        const int n0  = nb * 128;
        const int koff = kh << 10;     // k-window start (0 or 1024)

        __syncthreads();   // prior tile's LDS readers done before restaging

        // staging sources: thread c: row=c>>2, chunk=(c&3)^((row>>1)&3); 1 A + 1 B load
        const int srow  = tid >> 2;
        const int chunk = (tid & 3) ^ ((srow >> 1) & 3);
        size_t asrc, bsrc;
        {
            int entry = m0 + srow;
            if (MODE == 0) {
                int tok = (entry < cnt_e) ? tok_list[e * N_TOK + entry] : 0;
                asrc = (size_t)tok * K + chunk * 8;
            } else {
                asrc = (size_t)(offs_e + entry) * K + koff + chunk * 8;
            }
            bsrc = ((size_t)e * NCOL + n0 + srow) * K + koff + chunk * 8;
        }

        f32x4 acc[4][2];
#pragma unroll
        for (int m = 0; m < 4; ++m)
#pragma unroll
            for (int n = 0; n < 2; ++n)
                acc[m][n] = (f32x4){0.f, 0.f, 0.f, 0.f};

        auto STAGE = [&](int t, int b) {
            int k0 = t * 32;
            gload_lds16(A  + asrc + k0, &As[b][tid * 8]);
            gload_lds16(Bt + bsrc + k0, &Bs[b][tid * 8]);
        };

        auto COMPUTE = [&](int b) {
            bf16x8 af[4], bfr[2];
#pragma unroll
            for (int m = 0; m < 4; ++m) {
                int rr = wr + m * 16 + la;
                af[m] = *reinterpret_cast<const bf16x8*>(&As[b][(rr * 4 + (kc ^ ((rr >> 1) & 3))) * 8]);
            }
#pragma unroll
            for (int n = 0; n < 2; ++n) {
                int rr = wc + n * 16 + la;
                bfr[n] = *reinterpret_cast<const bf16x8*>(&Bs[b][(rr * 4 + (kc ^ ((rr >> 1) & 3))) * 8]);
            }
            __builtin_amdgcn_s_setprio(1);
#pragma unroll
            for (int m = 0; m < 4; ++m)
#pragma unroll
                for (int n = 0; n < 2; ++n)
                    acc[m][n] = __builtin_amdgcn_mfma_f32_16x16x32_bf16(af[m], bfr[n], acc[m][n], 0, 0, 0);
            __builtin_amdgcn_s_setprio(0);
        };

        const int nk = 32;             // 1024 K window / 32
        STAGE(0, 0);
        STAGE(1, 1);
        for (int t = 0; t < nk - 1; ++t) {
            asm volatile("s_waitcnt vmcnt(2)" ::: "memory");
            __builtin_amdgcn_s_barrier();
            if (t + 2 < nk) STAGE(t + 2, (t + 2) % 3);
            COMPUTE(t % 3);
        }
        asm volatile("s_waitcnt vmcnt(0)" ::: "memory");
        __builtin_amdgcn_s_barrier();
        COMPUTE((nk - 1) % 3);

        // epilogue: C/D layout col = lane&15, row = (lane>>4)*4 + j (HW-verified)
#pragma unroll
        for (int m = 0; m < 4; ++m) {
            int rbase = wr + m * 16 + (lane >> 4) * 4;
#pragma unroll
            for (int n = 0; n < 2; ++n) {
                int gcol = n0 + wc + n * 16 + la;
                float bi = (MODE == 1 && kh != 0) ? 0.f : bias[(size_t)e * NCOL + gcol];
#pragma unroll
                for (int jj = 0; jj < 4; ++jj) {
                    int entry = m0 + rbase + jj;
                    if (entry < cnt_e) {
                        float v = acc[m][n][jj] + bi;
                        if (MODE == 0) {
                            // gelu(tanh approx): tanh(u) = (t-1)/(t+1), t = exp2(2u*log2e)
                            float u = 0.7978845608028654f * (v + 0.044715f * v * v * v);
                            float t2 = __builtin_amdgcn_exp2f(2.8853900817779268f * u);
                            float g = v * (t2 / (t2 + 1.f));
                            hout[(size_t)(offs_e + entry) * FF + gcol] = f2bf(g);
                        } else {
                            int tok  = tok_list[e * N_TOK + entry];
                            float w  = w_list  [e * N_TOK + entry];
                            atomicAdd(&out[(size_t)tok * DIM + gcol], w * v);
                        }
                    }
                }
            }
        }
    }
}

extern "C" void kernel_launch(void* const* d_in, const int* in_sizes, int n_in,
                              void* d_out, int out_size, void* d_ws, size_t ws_size,
                              hipStream_t stream)
{
    const float* x  = (const float*)d_in[0];
    const float* Wr = (const float*)d_in[1];
    const float* br = (const float*)d_in[2];
    const float* W1 = (const float*)d_in[3];
    const float* b1 = (const float*)d_in[4];
    const float* W2 = (const float*)d_in[5];
    const float* b2 = (const float*)d_in[6];
    float* out = (float*)d_out;

    // workspace layout (~146 MB total)
    char* ws = (char*)d_ws;
    size_t off = 0;
    auto alloc = [&](size_t bytes) -> void* {
        void* p = ws + off;
        off = (off + bytes + 255) & ~(size_t)255;
        return p;
    };
    ushort_t* w1t = (ushort_t*)alloc((size_t)NE * DIM * FF * 2);          // 32 MB  [E][F][D]
    ushort_t* w2t = (ushort_t*)alloc((size_t)NE * DIM * FF * 2);          // 32 MB  [E][D][F]
    ushort_t* xb  = (ushort_t*)alloc((size_t)N_TOK * DIM * 2);            // 16 MB
    ushort_t* h   = (ushort_t*)alloc(((size_t)2 * N_TOK + 128) * FF * 2); // 64.5 MB (+slack)
    int*      cnt = (int*)alloc(NE * sizeof(int));
    int*      offs= (int*)alloc((NE + 1) * sizeof(int));
    int*   tok_list = (int*)alloc((size_t)NE * N_TOK * sizeof(int));
    float* w_list   = (float*)alloc((size_t)NE * N_TOK * sizeof(float));
    int*   tile_e   = (int*)alloc(256 * sizeof(int));
    int*   tile_m0  = (int*)alloc(256 * sizeof(int));
    int*   meta     = (int*)alloc(16 * sizeof(int));
    (void)ws_size; (void)in_sizes; (void)n_in;

    hipMemsetAsync(out, 0, (size_t)out_size * sizeof(float), stream);
    hipMemsetAsync(cnt, 0, NE * sizeof(int), stream);

    convert_x_kernel<<<(N_TOK * DIM) / (8 * 256), 256, 0, stream>>>(x, xb);
    transpose_conv_kernel<<<dim3(FF / 64, DIM / 64, NE), 256, 0, stream>>>(W1, w1t, DIM, FF);
    transpose_conv_kernel<<<dim3(DIM / 64, FF / 64, NE), 256, 0, stream>>>(W2, w2t, FF, DIM);
    router_kernel<<<N_TOK / 64, 256, 0, stream>>>(x, Wr, br, cnt, tok_list, w_list);
    scan_kernel<<<1, 64, 0, stream>>>(cnt, offs, tile_e, tile_m0, meta);

    moe_gemm_kernel<0><<<768, 512, 0, stream>>>(
        xb, w1t, b1, cnt, offs, tok_list, w_list, tile_e, tile_m0, meta, h, nullptr);
    moe_gemm_kernel<1><<<768, 512, 0, stream>>>(
        h, w2t, b2, cnt, offs, tok_list, w_list, tile_e, tile_m0, meta, nullptr, out);
}